// Round 6
// baseline (82.181 us; speedup 1.0000x reference)
//
#include <hip/hip_runtime.h>
#include <hip/hip_bf16.h>
#include <math.h>

// Problem constants (from reference)
#define B 8
#define S 512
#define A 4
#define N (S*A)          // 2048 points per batch for the LJ term
#define SIGMA 3.0f
#define HB_R0 2.9f
#define HB_COEF (-12.5f) // -0.5 / 0.2^2
#define EPS 1e-6f

// 256 producer blocks, 256 threads each (1 block/CU).
// Every block does one LJ unit: bid = b*32 + it*4 + jc
//   batch b = bid>>5, i-tile it = (bid>>2)&7 (256 i-points), j-chunk jc = bid&3 (512 j-points)
// Blocks [0,64)  additionally do one HB unit (8 batches x 2 i-tiles x 4 j-quarters).
// Blocks [64,72) additionally do aux moments for batch bid-64.
// Last block to bump the done-counter performs the final combine.
#define NPROD 256

// ws layout (floats) — ALL cross-block slots accessed only via relaxed
// agent-scope atomics (sc1: write-through to coherence point, no L2
// ownership, no wbl2 fences needed):
//   [0, 256)    LJ partial numerators (one per block)
//   [256, 320)  HB partial numerators (one per HB unit)
//   [320 + b*8 + k) aux: S1x,S1y,S1z,S2,M,Sm2,motor_num,motor_den
//   [448]       done counter (uint)
// Harness re-poisons ws to 0xAA before every launch (counter init
// 0xAAAAAAAAu handled explicitly; zero-init also handled).
#define WS_LJ   0
#define WS_HB   256
#define WS_AUX  320
#define WS_CNT  448
#define POISON_U 0xAAAAAAAAu

__device__ __forceinline__ float wave_reduce_sum(float v) {
    #pragma unroll
    for (int off = 32; off > 0; off >>= 1) v += __shfl_down(v, off, 64);
    return v;
}

// relaxed agent-scope = sc1 accesses at the coherence point; no fences emitted
__device__ __forceinline__ void slot_store(float* p, float v) {
    __hip_atomic_store(p, v, __ATOMIC_RELAXED, __HIP_MEMORY_SCOPE_AGENT);
}
__device__ __forceinline__ float slot_load(const float* p) {
    return __hip_atomic_load(p, __ATOMIC_RELAXED, __HIP_MEMORY_SCOPE_AGENT);
}

__global__ __launch_bounds__(256) void physics_fused(
        const float* __restrict__ coords,
        const float* __restrict__ motors,
        const float* __restrict__ mask,
        float* __restrict__ ws,
        float* __restrict__ out) {
    const int bid = blockIdx.x;
    const int tid = threadIdx.x;

    __shared__ float4 sj[512];      // staged j-points: (x,y,z,mask) — 8 KB
    __shared__ float  redbuf[32];   // 4 waves x up to 8 values
    __shared__ float  saux[64];
    __shared__ int    winflag;

    const int wid = tid >> 6, lane = tid & 63;
    unsigned int* counter = (unsigned int*)(ws + WS_CNT);

    // ================= phase 1: LJ (all 256 blocks) =================
    {
        const int b  = bid >> 5;
        const int it = (bid >> 2) & 7;
        const int jc = bid & 3;

        const float* cb = coords + (size_t)b * N * 3;
        const float* mb = mask + b * S;
        const int jlo = jc * 512;

        // stage 512 j-points: thread t loads jlo+t and jlo+256+t
        {
            const int j0 = jlo + tid;
            sj[tid]       = make_float4(cb[j0*3+0], cb[j0*3+1], cb[j0*3+2], mb[j0 >> 2]);
            const int j1 = j0 + 256;
            sj[tid + 256] = make_float4(cb[j1*3+0], cb[j1*3+1], cb[j1*3+2], mb[j1 >> 2]);
        }
        __syncthreads();

        const int i = it * 256 + tid;
        const float xi = cb[i*3+0], yi = cb[i*3+1], zi = cb[i*3+2];
        const float fmi = mb[i >> 2];

        float acc = 0.f;
        #pragma unroll 8
        for (int jj = 0; jj < 512; ++jj) {
            const float4 q = sj[jj];
            const float dx = xi - q.x;
            const float dy = yi - q.y;
            const float dz = zi - q.z;
            const float d2 = fmaf(dx, dx, fmaf(dy, dy, fmaf(dz, dz, EPS)));
            const float rr = __builtin_amdgcn_sqrtf(d2);
            const float ov = fmaxf(SIGMA - rr, 0.f);
            const float ov2 = ov * ov;
            acc = fmaf(ov2 * ov2, q.w, acc);
        }
        // remove i==j: i is inside this j-chunk iff (it>>1)==jc
        if ((it >> 1) == jc) {
            const float ovd = SIGMA - __builtin_amdgcn_sqrtf(EPS);
            const float o2 = ovd * ovd;
            acc -= fmi * (o2 * o2);
        }
        float v = wave_reduce_sum(fmi * acc);
        if (lane == 0) redbuf[wid] = v;
        __syncthreads();
        if (tid == 0)
            slot_store(ws + WS_LJ + bid, redbuf[0] + redbuf[1] + redbuf[2] + redbuf[3]);
        __syncthreads();   // before sj/redbuf reuse
    }

    // ================= phase 2: HB (blocks 0..63) / aux (64..71) =================
    if (bid < 64) {
        const int idx = bid;
        const int b  = idx >> 3;
        const int rr_ = idx & 7;
        const int it = rr_ >> 2;        // 0..1 (i tiles of 256)
        const int jh = rr_ & 3;         // 0..3 (j quarters of 128)

        const float* cb = coords + (size_t)b * S * A * 3;
        const float* mb = mask + b * S;
        const int jlo = jh * 128;

        if (tid < 128) {
            const int j = jlo + tid;    // Oc = atom 3
            sj[tid] = make_float4(cb[(j*4+3)*3+0], cb[(j*4+3)*3+1],
                                  cb[(j*4+3)*3+2], mb[j]);
        }
        __syncthreads();

        const int i = it * 256 + tid;   // Nc = atom 0
        const float xi = cb[(i*4+0)*3+0];
        const float yi = cb[(i*4+0)*3+1];
        const float zi = cb[(i*4+0)*3+2];
        const float mi = mb[i];

        float acc = 0.f;
        #pragma unroll 8
        for (int jj = 0; jj < 128; ++jj) {
            const float4 q = sj[jj];
            const float dx = xi - q.x;
            const float dy = yi - q.y;
            const float dz = zi - q.z;
            const float d2 = fmaf(dx, dx, fmaf(dy, dy, dz * dz)); // no EPS (ref)
            const float dist = __builtin_amdgcn_sqrtf(d2);
            const float t = dist - HB_R0;
            const float e = __expf(HB_COEF * (t * t));
            acc = fmaf(e, q.w, acc);
        }
        // subtract the |i-j| <= 2 band (range_mask==0 there)
        #pragma unroll
        for (int dj = -2; dj <= 2; ++dj) {
            const int j = i + dj;
            if (j >= jlo && j < jlo + 128) {
                const float4 q = sj[j - jlo];
                const float dx = xi - q.x;
                const float dy = yi - q.y;
                const float dz = zi - q.z;
                const float d2 = fmaf(dx, dx, fmaf(dy, dy, dz * dz));
                const float dist = __builtin_amdgcn_sqrtf(d2);
                const float t = dist - HB_R0;
                const float e = __expf(HB_COEF * (t * t));
                acc -= e * q.w;
            }
        }
        float v = wave_reduce_sum(mi * acc);
        if (lane == 0) redbuf[wid] = v;
        __syncthreads();
        if (tid == 0)
            slot_store(ws + WS_HB + idx, redbuf[0] + redbuf[1] + redbuf[2] + redbuf[3]);

    } else if (bid < 72) {
        const int b = bid - 64;
        const float* cb = coords + (size_t)b * S * A * 3;
        const float* mb = mask + b * S;

        float s1x = 0.f, s1y = 0.f, s1z = 0.f, s2 = 0.f, M = 0.f, Sm2 = 0.f;
        float mn = 0.f, md = 0.f;

        for (int s = tid; s < S; s += 256) {
            const float m = mb[s];
            const float* ca = cb + ((size_t)(s*4 + 1)) * 3;   // atom 1
            const float x = ca[0], y = ca[1], z = ca[2];
            s1x = fmaf(x, m, s1x);
            s1y = fmaf(y, m, s1y);
            s1z = fmaf(z, m, s1z);
            s2  = fmaf(fmaf(x, x, fmaf(y, y, z * z)), m, s2);
            M   += m;
            Sm2 = fmaf(m, m, Sm2);
            if (s < S - 1) {
                const float mm = m * mb[s + 1];
                const float4* m4 = (const float4*)(motors + ((size_t)b * S + s) * 8);
                const float4 a0 = m4[0], a1 = m4[1], b0 = m4[2], b1 = m4[3];
                float d = 0.f;
                float df;
                df = b0.x - a0.x; d = fmaf(df, df, d);
                df = b0.y - a0.y; d = fmaf(df, df, d);
                df = b0.z - a0.z; d = fmaf(df, df, d);
                df = b0.w - a0.w; d = fmaf(df, df, d);
                df = b1.x - a1.x; d = fmaf(df, df, d);
                df = b1.y - a1.y; d = fmaf(df, df, d);
                df = b1.z - a1.z; d = fmaf(df, df, d);
                df = b1.w - a1.w; d = fmaf(df, df, d);
                mn = fmaf(d, mm, mn);
                md += mm;
            }
        }

        float vals[8] = {s1x, s1y, s1z, s2, M, Sm2, mn, md};
        #pragma unroll
        for (int k = 0; k < 8; ++k) {
            float v = wave_reduce_sum(vals[k]);
            if (lane == 0) redbuf[wid * 8 + k] = v;
        }
        __syncthreads();
        if (tid < 8) {
            const float t = redbuf[tid] + redbuf[8 + tid] + redbuf[16 + tid] + redbuf[24 + tid];
            slot_store(ws + WS_AUX + b * 8 + tid, t);
        }
    }

    // ================= signal (relaxed, fence-free) =================
    __syncthreads();
    if (tid == 0) {
        // Ensure this block's sc1 slot-stores are ACKed at the coherence
        // point before the counter bump issues: bare vmcnt wait, no wbl2.
        __atomic_signal_fence(__ATOMIC_SEQ_CST);
        __builtin_amdgcn_s_waitcnt(0);
        __atomic_signal_fence(__ATOMIC_SEQ_CST);
        const unsigned int ret = __hip_atomic_fetch_add(
            counter, 1u, __ATOMIC_RELAXED, __HIP_MEMORY_SCOPE_AGENT);
        winflag = (ret == POISON_U + (NPROD - 1u)) ||
                  (ret == (unsigned int)(NPROD - 1)) ? 1 : 0;
    }
    __syncthreads();

    // ================= last block combines (whole block) =================
    if (winflag) {
        float lj = slot_load(ws + WS_LJ + tid);
        float hb = (tid < 64) ? slot_load(ws + WS_HB + tid) : 0.f;
        if (tid < 64) saux[tid] = slot_load(ws + WS_AUX + tid);

        lj = wave_reduce_sum(lj);
        hb = wave_reduce_sum(hb);
        if (lane == 0) { redbuf[wid * 2 + 0] = lj; redbuf[wid * 2 + 1] = hb; }
        __syncthreads();

        if (tid == 0) {
            const float lj_num = redbuf[0] + redbuf[2] + redbuf[4] + redbuf[6];
            const float hb_num = redbuf[1] + redbuf[3] + redbuf[5] + redbuf[7];

            float lj_den = 0.f, masksum = 0.f, mnum = 0.f, mden = 0.f, rg = 0.f;
            #pragma unroll
            for (int b = 0; b < B; ++b) {
                const float* p = saux + b * 8;
                const float M = p[4], Sm2 = p[5];
                lj_den  += 16.f * M * M - 4.f * Sm2;   // sum pair_mask, analytic
                masksum += M;
                mnum    += p[6];
                mden    += p[7];
                const float Me = M + EPS;
                const float mx = p[0] / Me, my = p[1] / Me, mz = p[2] / Me;
                // sum m*|ca-mean|^2 = S2 - 2 mean.S1 + |mean|^2 * M
                const float d2sum = p[3] - 2.f * (mx * p[0] + my * p[1] + mz * p[2])
                                  + (mx * mx + my * my + mz * mz) * M;
                rg += d2sum / Me;
            }
            rg *= (1.f / (float)B);

            const float ljv   = lj_num / (lj_den + EPS);
            const float hbv   = -hb_num / (masksum + EPS);
            const float motor = mnum / (mden + EPS);
            out[0] = ljv + 0.5f * hbv + 0.1f * motor + 0.05f * rg;
        }
    }
}

extern "C" void kernel_launch(void* const* d_in, const int* in_sizes, int n_in,
                              void* d_out, int out_size, void* d_ws, size_t ws_size,
                              hipStream_t stream) {
    const float* coords = (const float*)d_in[0];
    const float* motors = (const float*)d_in[1];
    const float* mask   = (const float*)d_in[2];
    float* ws  = (float*)d_ws;
    float* out = (float*)d_out;

    physics_fused<<<NPROD, 256, 0, stream>>>(coords, motors, mask, ws, out);
}

// Round 7
// 81.446 us; speedup vs baseline: 1.0090x; 1.0090x over previous
//
#include <hip/hip_runtime.h>
#include <hip/hip_bf16.h>
#include <math.h>

// Problem constants (from reference)
#define B 8
#define S 512
#define A 4
#define N (S*A)          // 2048 points per batch for the LJ term
#define SIGMA 3.0f
#define HB_R0 2.9f
#define HB_COEF (-12.5f) // -0.5 / 0.2^2
#define EPS 1e-6f

// 256 producer blocks, 256 threads each (exactly 1 block/CU -> all co-resident).
// Every block does one LJ unit: bid = b*32 + it*4 + jc
//   batch b = bid>>5, i-tile it = (bid>>2)&7 (256 i-pts), j-chunk jc = bid&3 (512 j-pts)
// Blocks [0,64)  additionally do one HB unit (8 batches x 2 i-tiles x 4 j-quarters).
// Blocks [64,72) additionally do aux moments for batch bid-64.
// Block 255 (dispatched last, co-resident) polls the tagged slots and combines.
//
// Cross-block communication: ONE relaxed agent-scope 64-bit store per value,
// packed (TAG<<32)|float_bits into a UNIQUE slot. No same-line RMWs (R4-R6
// showed a shared counter costs ~100ns x #blocks), no acquire/invalidate ops
// (R4 showed an acquire-spin is an L2-invalidation storm). Tag+value travel
// in one store so no ordering fences are needed anywhere.
#define NPROD 256
#define TAG 0x3C96F1E5u   // != 0xAAAAAAAA harness poison

// ws as u64 slots:
//   [0,256)   LJ tagged partials (one per block)
//   [256,320) HB tagged partials
//   [320,384) aux tagged: b*8 + {S1x,S1y,S1z,S2,M,Sm2,motor_num,motor_den}
#define SL_LJ  0
#define SL_HB  256
#define SL_AUX 320

__device__ __forceinline__ float wave_reduce_sum(float v) {
    #pragma unroll
    for (int off = 32; off > 0; off >>= 1) v += __shfl_down(v, off, 64);
    return v;
}

__device__ __forceinline__ void publish(unsigned long long* slot, float v) {
    const unsigned long long pk =
        ((unsigned long long)TAG << 32) | (unsigned long long)__float_as_uint(v);
    __hip_atomic_store(slot, pk, __ATOMIC_RELAXED, __HIP_MEMORY_SCOPE_AGENT);
}
__device__ __forceinline__ float poll(const unsigned long long* slot) {
    unsigned long long v;
    while (((v = __hip_atomic_load(slot, __ATOMIC_RELAXED,
                                   __HIP_MEMORY_SCOPE_AGENT)) >> 32) != TAG)
        __builtin_amdgcn_s_sleep(2);
    return __uint_as_float((unsigned int)(v & 0xFFFFFFFFull));
}

__global__ __launch_bounds__(256) void physics_fused(
        const float* __restrict__ coords,
        const float* __restrict__ motors,
        const float* __restrict__ mask,
        unsigned long long* __restrict__ slots,
        float* __restrict__ out) {
    const int bid = blockIdx.x;
    const int tid = threadIdx.x;

    __shared__ float4 sj[512];      // staged j-points: (x,y,z,mask) — 8 KB
    __shared__ float  redbuf[32];   // 4 waves x up to 8 values
    __shared__ float  saux[64];

    const int wid = tid >> 6, lane = tid & 63;

    // ================= phase 1: LJ (all 256 blocks) =================
    {
        const int b  = bid >> 5;
        const int it = (bid >> 2) & 7;
        const int jc = bid & 3;

        const float* cb = coords + (size_t)b * N * 3;
        const float* mb = mask + b * S;
        const int jlo = jc * 512;

        // stage 512 j-points: thread t loads jlo+t and jlo+256+t
        {
            const int j0 = jlo + tid;
            sj[tid]       = make_float4(cb[j0*3+0], cb[j0*3+1], cb[j0*3+2], mb[j0 >> 2]);
            const int j1 = j0 + 256;
            sj[tid + 256] = make_float4(cb[j1*3+0], cb[j1*3+1], cb[j1*3+2], mb[j1 >> 2]);
        }
        __syncthreads();

        const int i = it * 256 + tid;
        const float xi = cb[i*3+0], yi = cb[i*3+1], zi = cb[i*3+2];
        const float fmi = mb[i >> 2];

        float acc = 0.f;
        #pragma unroll 8
        for (int jj = 0; jj < 512; ++jj) {
            const float4 q = sj[jj];
            const float dx = xi - q.x;
            const float dy = yi - q.y;
            const float dz = zi - q.z;
            const float d2 = fmaf(dx, dx, fmaf(dy, dy, fmaf(dz, dz, EPS)));
            const float rr = __builtin_amdgcn_sqrtf(d2);
            const float ov = fmaxf(SIGMA - rr, 0.f);
            const float ov2 = ov * ov;
            acc = fmaf(ov2 * ov2, q.w, acc);
        }
        // remove i==j: i is inside this j-chunk iff (it>>1)==jc
        if ((it >> 1) == jc) {
            const float ovd = SIGMA - __builtin_amdgcn_sqrtf(EPS);
            const float o2 = ovd * ovd;
            acc -= fmi * (o2 * o2);
        }
        float v = wave_reduce_sum(fmi * acc);
        if (lane == 0) redbuf[wid] = v;
        __syncthreads();
        if (tid == 0)
            publish(slots + SL_LJ + bid, redbuf[0] + redbuf[1] + redbuf[2] + redbuf[3]);
        __syncthreads();   // before sj/redbuf reuse
    }

    // ================= phase 2: HB (blocks 0..63) / aux (64..71) =================
    if (bid < 64) {
        const int idx = bid;
        const int b  = idx >> 3;
        const int rr_ = idx & 7;
        const int it = rr_ >> 2;        // 0..1 (i tiles of 256)
        const int jh = rr_ & 3;         // 0..3 (j quarters of 128)

        const float* cb = coords + (size_t)b * S * A * 3;
        const float* mb = mask + b * S;
        const int jlo = jh * 128;

        if (tid < 128) {
            const int j = jlo + tid;    // Oc = atom 3
            sj[tid] = make_float4(cb[(j*4+3)*3+0], cb[(j*4+3)*3+1],
                                  cb[(j*4+3)*3+2], mb[j]);
        }
        __syncthreads();

        const int i = it * 256 + tid;   // Nc = atom 0
        const float xi = cb[(i*4+0)*3+0];
        const float yi = cb[(i*4+0)*3+1];
        const float zi = cb[(i*4+0)*3+2];
        const float mi = mb[i];

        float acc = 0.f;
        #pragma unroll 8
        for (int jj = 0; jj < 128; ++jj) {
            const float4 q = sj[jj];
            const float dx = xi - q.x;
            const float dy = yi - q.y;
            const float dz = zi - q.z;
            const float d2 = fmaf(dx, dx, fmaf(dy, dy, dz * dz)); // no EPS (ref)
            const float dist = __builtin_amdgcn_sqrtf(d2);
            const float t = dist - HB_R0;
            const float e = __expf(HB_COEF * (t * t));
            acc = fmaf(e, q.w, acc);
        }
        // subtract the |i-j| <= 2 band (range_mask==0 there)
        #pragma unroll
        for (int dj = -2; dj <= 2; ++dj) {
            const int j = i + dj;
            if (j >= jlo && j < jlo + 128) {
                const float4 q = sj[j - jlo];
                const float dx = xi - q.x;
                const float dy = yi - q.y;
                const float dz = zi - q.z;
                const float d2 = fmaf(dx, dx, fmaf(dy, dy, dz * dz));
                const float dist = __builtin_amdgcn_sqrtf(d2);
                const float t = dist - HB_R0;
                const float e = __expf(HB_COEF * (t * t));
                acc -= e * q.w;
            }
        }
        float v = wave_reduce_sum(mi * acc);
        if (lane == 0) redbuf[wid] = v;
        __syncthreads();
        if (tid == 0)
            publish(slots + SL_HB + idx, redbuf[0] + redbuf[1] + redbuf[2] + redbuf[3]);

    } else if (bid < 72) {
        const int b = bid - 64;
        const float* cb = coords + (size_t)b * S * A * 3;
        const float* mb = mask + b * S;

        float s1x = 0.f, s1y = 0.f, s1z = 0.f, s2 = 0.f, M = 0.f, Sm2 = 0.f;
        float mn = 0.f, md = 0.f;

        for (int s = tid; s < S; s += 256) {
            const float m = mb[s];
            const float* ca = cb + ((size_t)(s*4 + 1)) * 3;   // atom 1
            const float x = ca[0], y = ca[1], z = ca[2];
            s1x = fmaf(x, m, s1x);
            s1y = fmaf(y, m, s1y);
            s1z = fmaf(z, m, s1z);
            s2  = fmaf(fmaf(x, x, fmaf(y, y, z * z)), m, s2);
            M   += m;
            Sm2 = fmaf(m, m, Sm2);
            if (s < S - 1) {
                const float mm = m * mb[s + 1];
                const float4* m4 = (const float4*)(motors + ((size_t)b * S + s) * 8);
                const float4 a0 = m4[0], a1 = m4[1], b0 = m4[2], b1 = m4[3];
                float d = 0.f;
                float df;
                df = b0.x - a0.x; d = fmaf(df, df, d);
                df = b0.y - a0.y; d = fmaf(df, df, d);
                df = b0.z - a0.z; d = fmaf(df, df, d);
                df = b0.w - a0.w; d = fmaf(df, df, d);
                df = b1.x - a1.x; d = fmaf(df, df, d);
                df = b1.y - a1.y; d = fmaf(df, df, d);
                df = b1.z - a1.z; d = fmaf(df, df, d);
                df = b1.w - a1.w; d = fmaf(df, df, d);
                mn = fmaf(d, mm, mn);
                md += mm;
            }
        }

        float vals[8] = {s1x, s1y, s1z, s2, M, Sm2, mn, md};
        #pragma unroll
        for (int k = 0; k < 8; ++k) {
            float v = wave_reduce_sum(vals[k]);
            if (lane == 0) redbuf[wid * 8 + k] = v;
        }
        __syncthreads();
        if (tid < 8) {
            const float t = redbuf[tid] + redbuf[8 + tid] + redbuf[16 + tid] + redbuf[24 + tid];
            publish(slots + SL_AUX + b * 8 + tid, t);
        }
    }

    // ================= block 255: poll tagged slots, combine =================
    if (bid == NPROD - 1) {
        // All 256 blocks are co-resident (1/CU), so polling cannot deadlock.
        // Relaxed sc1 loads: no cache-invalidate per iteration, no RMWs.
        float lj = poll(slots + SL_LJ + tid);                 // 256 slots
        float hb = (tid < 64) ? poll(slots + SL_HB + tid) : 0.f;
        if (tid >= 64 && tid < 128)
            saux[tid - 64] = poll(slots + SL_AUX + (tid - 64));
        __syncthreads();

        lj = wave_reduce_sum(lj);
        hb = wave_reduce_sum(hb);
        if (lane == 0) { redbuf[wid * 2 + 0] = lj; redbuf[wid * 2 + 1] = hb; }
        __syncthreads();

        if (tid == 0) {
            const float lj_num = redbuf[0] + redbuf[2] + redbuf[4] + redbuf[6];
            const float hb_num = redbuf[1] + redbuf[3] + redbuf[5] + redbuf[7];

            float lj_den = 0.f, masksum = 0.f, mnum = 0.f, mden = 0.f, rg = 0.f;
            #pragma unroll
            for (int b = 0; b < B; ++b) {
                const float* p = saux + b * 8;
                const float M = p[4], Sm2 = p[5];
                lj_den  += 16.f * M * M - 4.f * Sm2;   // sum pair_mask, analytic
                masksum += M;
                mnum    += p[6];
                mden    += p[7];
                const float Me = M + EPS;
                const float mx = p[0] / Me, my = p[1] / Me, mz = p[2] / Me;
                // sum m*|ca-mean|^2 = S2 - 2 mean.S1 + |mean|^2 * M
                const float d2sum = p[3] - 2.f * (mx * p[0] + my * p[1] + mz * p[2])
                                  + (mx * mx + my * my + mz * mz) * M;
                rg += d2sum / Me;
            }
            rg *= (1.f / (float)B);

            const float ljv   = lj_num / (lj_den + EPS);
            const float hbv   = -hb_num / (masksum + EPS);
            const float motor = mnum / (mden + EPS);
            out[0] = ljv + 0.5f * hbv + 0.1f * motor + 0.05f * rg;
        }
    }
}

extern "C" void kernel_launch(void* const* d_in, const int* in_sizes, int n_in,
                              void* d_out, int out_size, void* d_ws, size_t ws_size,
                              hipStream_t stream) {
    const float* coords = (const float*)d_in[0];
    const float* motors = (const float*)d_in[1];
    const float* mask   = (const float*)d_in[2];
    unsigned long long* slots = (unsigned long long*)d_ws;
    float* out = (float*)d_out;

    physics_fused<<<NPROD, 256, 0, stream>>>(coords, motors, mask, slots, out);
}